// Round 4
// baseline (94.642 us; speedup 1.0000x reference)
//
#include <hip/hip_runtime.h>

#define N_PER_BATCH (512 * 512)        // 262144
#define BLOCKS_PER_BATCH 32
#define NBATCH 64
#define THREADS 256
#define GRID (NBATCH * BLOCKS_PER_BATCH)   // 2048

// d_ws layout (floats): [0] = ticket counter (as uint); partials at float
// offset 64: P[2048] | T[2048] | I[2048], indexed cb*NBATCH+b so the final
// reduction reads lane-contiguous in b.

__global__ __launch_bounds__(THREADS) void dice_fused(
    const float* __restrict__ pred, const float* __restrict__ tgt,
    float* __restrict__ ws, float* __restrict__ out) {
    const int b  = blockIdx.x >> 5;          // / BLOCKS_PER_BATCH
    const int cb = blockIdx.x & 31;          // % BLOCKS_PER_BATCH

    const float4* p4 = reinterpret_cast<const float4*>(pred + (size_t)b * N_PER_BATCH);
    const float4* t4 = reinterpret_cast<const float4*>(tgt  + (size_t)b * N_PER_BATCH);
    const int base = cb * (N_PER_BATCH / BLOCKS_PER_BATCH / 4);  // 2048 float4/block

    float4 p[8], t[8];
#pragma unroll
    for (int i = 0; i < 8; ++i) p[i] = p4[base + i * THREADS + threadIdx.x];
#pragma unroll
    for (int i = 0; i < 8; ++i) t[i] = t4[base + i * THREADS + threadIdx.x];

    float ps = 0.f, ts = 0.f, is = 0.f;
#pragma unroll
    for (int i = 0; i < 8; ++i) {
        ps += (p[i].x + p[i].y) + (p[i].z + p[i].w);
        ts += (t[i].x + t[i].y) + (t[i].z + t[i].w);
        is += (p[i].x * t[i].x + p[i].y * t[i].y) + (p[i].z * t[i].z + p[i].w * t[i].w);
    }

#pragma unroll
    for (int off = 32; off > 0; off >>= 1) {
        ps += __shfl_down(ps, off, 64);
        ts += __shfl_down(ts, off, 64);
        is += __shfl_down(is, off, 64);
    }

    __shared__ float s[3][4];
    __shared__ int amLast;
    const int wid  = threadIdx.x >> 6;
    const int lane = threadIdx.x & 63;
    if (lane == 0) { s[0][wid] = ps; s[1][wid] = ts; s[2][wid] = is; }
    __syncthreads();

    unsigned* counter = reinterpret_cast<unsigned*>(ws);
    float* P = ws + 64;
    float* T = P + GRID;
    float* I = T + GRID;

    if (threadIdx.x == 0) {
        const float Pv = (s[0][0] + s[0][1]) + (s[0][2] + s[0][3]);
        const float Tv = (s[1][0] + s[1][1]) + (s[1][2] + s[1][3]);
        const float Iv = (s[2][0] + s[2][1]) + (s[2][2] + s[2][3]);
        const int idx = cb * NBATCH + b;
        // agent-scope stores, then release via the ticket RMW (Guideline 16)
        __hip_atomic_store(&P[idx], Pv, __ATOMIC_RELAXED, __HIP_MEMORY_SCOPE_AGENT);
        __hip_atomic_store(&T[idx], Tv, __ATOMIC_RELAXED, __HIP_MEMORY_SCOPE_AGENT);
        __hip_atomic_store(&I[idx], Iv, __ATOMIC_RELAXED, __HIP_MEMORY_SCOPE_AGENT);
        const unsigned old = __hip_atomic_fetch_add(counter, 1u, __ATOMIC_ACQ_REL,
                                                    __HIP_MEMORY_SCOPE_AGENT);
        amLast = (old == GRID - 1) ? 1 : 0;
    }
    __syncthreads();
    if (!amLast) return;   // 2047 blocks exit here; no waiting, no deadlock

    // ---- final reduction by the single last-arriving block ----
    // acquire fence pairs with the release half of every block's ticket RMW
    __hip_atomic_fetch_add(counter, 0u, __ATOMIC_ACQUIRE, __HIP_MEMORY_SCOPE_AGENT);

    const int g = threadIdx.x >> 6;   // 4 groups; lane owns batch `lane`
    float Pb = 0.f, Tb = 0.f, Ib = 0.f;
#pragma unroll
    for (int c = 0; c < 8; ++c) {
        const int idx = (g * 8 + c) * NBATCH + lane;
        Pb += __hip_atomic_load(&P[idx], __ATOMIC_RELAXED, __HIP_MEMORY_SCOPE_AGENT);
        Tb += __hip_atomic_load(&T[idx], __ATOMIC_RELAXED, __HIP_MEMORY_SCOPE_AGENT);
        Ib += __hip_atomic_load(&I[idx], __ATOMIC_RELAXED, __HIP_MEMORY_SCOPE_AGENT);
    }
    __shared__ float r[3][4][64];
    r[0][g][lane] = Pb; r[1][g][lane] = Tb; r[2][g][lane] = Ib;
    __syncthreads();
    if (threadIdx.x < 64) {
        const float Ps = (r[0][0][lane] + r[0][1][lane]) + (r[0][2][lane] + r[0][3][lane]);
        const float Ts = (r[1][0][lane] + r[1][1][lane]) + (r[1][2][lane] + r[1][3][lane]);
        const float Is = (r[2][0][lane] + r[2][1][lane]) + (r[2][2][lane] + r[2][3][lane]);
        const float dice_loss = 1.0f - (2.0f * Is + 1.0f) / (Ps + Ts + 1.0f);
        const float zero_loss = Ps / (float)N_PER_BATCH;
        // target is 0/1 -> Ts is an exact integer in fp32, ==0 test is exact
        float loss = (Ts == 0.0f) ? zero_loss : dice_loss;
#pragma unroll
        for (int off = 32; off > 0; off >>= 1) loss += __shfl_down(loss, off, 64);
        if (lane == 0) out[0] = loss * (1.0f / (float)NBATCH);
    }
}

extern "C" void kernel_launch(void* const* d_in, const int* in_sizes, int n_in,
                              void* d_out, int out_size, void* d_ws, size_t ws_size,
                              hipStream_t stream) {
    const float* pred = (const float*)d_in[0];
    const float* tgt  = (const float*)d_in[1];
    float* out = (float*)d_out;
    float* ws  = (float*)d_ws;   // needs 256 B + 3*2048*4 B ≈ 24.8 KiB

    // reset the ticket counter every launch (graph-capturable async memset)
    hipMemsetAsync(d_ws, 0, sizeof(unsigned), stream);
    dice_fused<<<GRID, THREADS, 0, stream>>>(pred, tgt, ws, out);
}

// Round 5
// 43.100 us; speedup vs baseline: 2.1959x; 2.1959x over previous
//
#include <hip/hip_runtime.h>

#define N_PER_BATCH (512 * 512)        // 262144
#define BLOCKS_PER_BATCH 32
#define NBATCH 64
#define THREADS 256
#define GRID (NBATCH * BLOCKS_PER_BATCH)   // 2048

// d_ws layout (floats): [0] = ticket counter (as uint); partials at float
// offset 64: P[2048] | T[2048] | I[2048], indexed cb*NBATCH+b so the final
// reduction reads lane-contiguous in b.
//
// Sync design (Guideline 16, learned from R4's 145us blowup):
// NO acq_rel atomics -> compiler emits no L2 writeback/invalidate.
// Partials are RELAXED agent-scope atomic stores (sc1: performed at the
// coherence point, never dirty in a local L2). Thread0 orders them before
// the ticket increment with an explicit s_waitcnt vmcnt(0). The last block
// reads them back with RELAXED agent-scope atomic loads (sc1: served from
// the coherence point). Observing ticket==GRID-1 implies every block's
// partial stores completed at the coherence point.

__global__ __launch_bounds__(THREADS) void dice_fused(
    const float* __restrict__ pred, const float* __restrict__ tgt,
    float* __restrict__ ws, float* __restrict__ out) {
    const int b  = blockIdx.x >> 5;          // / BLOCKS_PER_BATCH
    const int cb = blockIdx.x & 31;          // % BLOCKS_PER_BATCH

    const float4* p4 = reinterpret_cast<const float4*>(pred + (size_t)b * N_PER_BATCH);
    const float4* t4 = reinterpret_cast<const float4*>(tgt  + (size_t)b * N_PER_BATCH);
    const int base = cb * (N_PER_BATCH / BLOCKS_PER_BATCH / 4);  // 2048 float4/block

    float4 p[8], t[8];
#pragma unroll
    for (int i = 0; i < 8; ++i) p[i] = p4[base + i * THREADS + threadIdx.x];
#pragma unroll
    for (int i = 0; i < 8; ++i) t[i] = t4[base + i * THREADS + threadIdx.x];

    float ps = 0.f, ts = 0.f, is = 0.f;
#pragma unroll
    for (int i = 0; i < 8; ++i) {
        ps += (p[i].x + p[i].y) + (p[i].z + p[i].w);
        ts += (t[i].x + t[i].y) + (t[i].z + t[i].w);
        is += (p[i].x * t[i].x + p[i].y * t[i].y) + (p[i].z * t[i].z + p[i].w * t[i].w);
    }

#pragma unroll
    for (int off = 32; off > 0; off >>= 1) {
        ps += __shfl_down(ps, off, 64);
        ts += __shfl_down(ts, off, 64);
        is += __shfl_down(is, off, 64);
    }

    __shared__ float s[3][4];
    __shared__ int amLast;
    const int wid  = threadIdx.x >> 6;
    const int lane = threadIdx.x & 63;
    if (lane == 0) { s[0][wid] = ps; s[1][wid] = ts; s[2][wid] = is; }
    __syncthreads();

    unsigned* counter = reinterpret_cast<unsigned*>(ws);
    float* P = ws + 64;
    float* T = P + GRID;
    float* I = T + GRID;

    if (threadIdx.x == 0) {
        const float Pv = (s[0][0] + s[0][1]) + (s[0][2] + s[0][3]);
        const float Tv = (s[1][0] + s[1][1]) + (s[1][2] + s[1][3]);
        const float Iv = (s[2][0] + s[2][1]) + (s[2][2] + s[2][3]);
        const int idx = cb * NBATCH + b;
        // relaxed agent-scope atomic stores: performed at the coherence
        // point (sc1), no cache maintenance emitted
        __hip_atomic_store(&P[idx], Pv, __ATOMIC_RELAXED, __HIP_MEMORY_SCOPE_AGENT);
        __hip_atomic_store(&T[idx], Tv, __ATOMIC_RELAXED, __HIP_MEMORY_SCOPE_AGENT);
        __hip_atomic_store(&I[idx], Iv, __ATOMIC_RELAXED, __HIP_MEMORY_SCOPE_AGENT);
        // hand-rolled release: wait for the three stores to complete at the
        // coherence point, THEN publish via the ticket. No wbl2 needed since
        // nothing above sits dirty in a local L2.
        asm volatile("s_waitcnt vmcnt(0)" ::: "memory");
        const unsigned old = __hip_atomic_fetch_add(counter, 1u, __ATOMIC_RELAXED,
                                                    __HIP_MEMORY_SCOPE_AGENT);
        amLast = (old == GRID - 1) ? 1 : 0;
    }
    __syncthreads();
    if (!amLast) return;   // 2047 blocks exit; no spinning, no deadlock

    // ---- final reduction by the single last-arriving block ----
    const int g = threadIdx.x >> 6;   // 4 groups; lane owns batch `lane`
    float Pb = 0.f, Tb = 0.f, Ib = 0.f;
#pragma unroll
    for (int c = 0; c < 8; ++c) {
        const int idx = (g * 8 + c) * NBATCH + lane;
        Pb += __hip_atomic_load(&P[idx], __ATOMIC_RELAXED, __HIP_MEMORY_SCOPE_AGENT);
        Tb += __hip_atomic_load(&T[idx], __ATOMIC_RELAXED, __HIP_MEMORY_SCOPE_AGENT);
        Ib += __hip_atomic_load(&I[idx], __ATOMIC_RELAXED, __HIP_MEMORY_SCOPE_AGENT);
    }
    __shared__ float r[3][4][64];
    r[0][g][lane] = Pb; r[1][g][lane] = Tb; r[2][g][lane] = Ib;
    __syncthreads();
    if (threadIdx.x < 64) {
        const float Ps = (r[0][0][lane] + r[0][1][lane]) + (r[0][2][lane] + r[0][3][lane]);
        const float Ts = (r[1][0][lane] + r[1][1][lane]) + (r[1][2][lane] + r[1][3][lane]);
        const float Is = (r[2][0][lane] + r[2][1][lane]) + (r[2][2][lane] + r[2][3][lane]);
        const float dice_loss = 1.0f - (2.0f * Is + 1.0f) / (Ps + Ts + 1.0f);
        const float zero_loss = Ps / (float)N_PER_BATCH;
        // target is 0/1 -> Ts is an exact integer in fp32, ==0 test is exact
        float loss = (Ts == 0.0f) ? zero_loss : dice_loss;
#pragma unroll
        for (int off = 32; off > 0; off >>= 1) loss += __shfl_down(loss, off, 64);
        if (lane == 0) out[0] = loss * (1.0f / (float)NBATCH);
    }
}

extern "C" void kernel_launch(void* const* d_in, const int* in_sizes, int n_in,
                              void* d_out, int out_size, void* d_ws, size_t ws_size,
                              hipStream_t stream) {
    const float* pred = (const float*)d_in[0];
    const float* tgt  = (const float*)d_in[1];
    float* out = (float*)d_out;
    float* ws  = (float*)d_ws;   // needs 256 B + 3*2048*4 B ~= 24.8 KiB

    // reset the ticket counter every launch (graph-capturable async memset)
    hipMemsetAsync(d_ws, 0, sizeof(unsigned), stream);
    dice_fused<<<GRID, THREADS, 0, stream>>>(pred, tgt, ws, out);
}

// Round 6
// 32.163 us; speedup vs baseline: 2.9426x; 1.3400x over previous
//
#include <hip/hip_runtime.h>

#define N_PER_BATCH (512 * 512)        // 262144
#define BPB 32                          // blocks per batch
#define NBATCH 64
#define THREADS 256
#define GRID (NBATCH * BPB)             // 2048

// d_ws layout:
//   uint  l1[b]   at u32 index b*16   (64 B apart, b in [0,64))   -- level-1 tickets
//   uint  l2      at u32 index 1024                               -- level-2 ticket
//   float loss[64] at f32 index 1088
//   float P[2048]  at f32 index 1280   (indexed b*BPB+cb)
//   float T[2048]  at f32 index 3328
//   float I[2048]  at f32 index 5376   -- total ~29 KiB
// Only the counter region [0, 4160 B) needs zeroing per launch.
//
// Sync design (validated in R5): all cross-block data moves via RELAXED
// agent-scope atomics (sc1 -> performed at the coherence point, no cache
// maintenance emitted), ordered before each ticket increment by an explicit
// s_waitcnt vmcnt(0). Hierarchical tickets avoid R5's 17us same-line
// atomic queueing (2048 ops on one line -> max 32 ops/line + 64 ops/line).

#define L1_STRIDE_U32 16
#define L2_OFF_U32    1024
#define LOSS_OFF      1088
#define P_OFF         1280
#define T_OFF         (P_OFF + GRID)
#define I_OFF         (T_OFF + GRID)
#define CLEAR_BYTES   4160

__global__ __launch_bounds__(THREADS) void dice_fused(
    const float* __restrict__ pred, const float* __restrict__ tgt,
    float* __restrict__ ws, float* __restrict__ out) {
    const int b  = blockIdx.x >> 5;          // / BPB
    const int cb = blockIdx.x & 31;          // % BPB

    const float4* p4 = reinterpret_cast<const float4*>(pred + (size_t)b * N_PER_BATCH);
    const float4* t4 = reinterpret_cast<const float4*>(tgt  + (size_t)b * N_PER_BATCH);
    const int base = cb * (N_PER_BATCH / BPB / 4);   // 2048 float4 per block

    float4 p[8], t[8];
#pragma unroll
    for (int i = 0; i < 8; ++i) p[i] = p4[base + i * THREADS + threadIdx.x];
#pragma unroll
    for (int i = 0; i < 8; ++i) t[i] = t4[base + i * THREADS + threadIdx.x];

    float ps = 0.f, ts = 0.f, is = 0.f;
#pragma unroll
    for (int i = 0; i < 8; ++i) {
        ps += (p[i].x + p[i].y) + (p[i].z + p[i].w);
        ts += (t[i].x + t[i].y) + (t[i].z + t[i].w);
        is += (p[i].x * t[i].x + p[i].y * t[i].y) + (p[i].z * t[i].z + p[i].w * t[i].w);
    }

#pragma unroll
    for (int off = 32; off > 0; off >>= 1) {
        ps += __shfl_down(ps, off, 64);
        ts += __shfl_down(ts, off, 64);
        is += __shfl_down(is, off, 64);
    }

    __shared__ float s[3][4];
    __shared__ int sLast;
    {
        const int wid  = threadIdx.x >> 6;
        const int lane = threadIdx.x & 63;
        if (lane == 0) { s[0][wid] = ps; s[1][wid] = ts; s[2][wid] = is; }
    }
    __syncthreads();

    unsigned* u = reinterpret_cast<unsigned*>(ws);

    if (threadIdx.x == 0) {
        const float Pv = (s[0][0] + s[0][1]) + (s[0][2] + s[0][3]);
        const float Tv = (s[1][0] + s[1][1]) + (s[1][2] + s[1][3]);
        const float Iv = (s[2][0] + s[2][1]) + (s[2][2] + s[2][3]);
        const int idx = b * BPB + cb;
        __hip_atomic_store(&ws[P_OFF + idx], Pv, __ATOMIC_RELAXED, __HIP_MEMORY_SCOPE_AGENT);
        __hip_atomic_store(&ws[T_OFF + idx], Tv, __ATOMIC_RELAXED, __HIP_MEMORY_SCOPE_AGENT);
        __hip_atomic_store(&ws[I_OFF + idx], Iv, __ATOMIC_RELAXED, __HIP_MEMORY_SCOPE_AGENT);
        // publish-then-ticket: stores complete at the coherence point first
        asm volatile("s_waitcnt vmcnt(0)" ::: "memory");
        const unsigned old = __hip_atomic_fetch_add(&u[b * L1_STRIDE_U32], 1u,
                                                    __ATOMIC_RELAXED, __HIP_MEMORY_SCOPE_AGENT);
        sLast = (old == BPB - 1) ? 1 : 0;
    }
    __syncthreads();
    if (!sLast) return;          // 31 of 32 blocks per batch exit here
    if (threadIdx.x >= 64) return;   // finisher work fits in wave 0

    // ---- batch finisher: reduce this batch's 32 partials ----
    const int lane = threadIdx.x;    // 0..63
    float pv = 0.f, tv = 0.f, iv = 0.f;
    if (lane < BPB) {
        const int idx = b * BPB + lane;
        pv = __hip_atomic_load(&ws[P_OFF + idx], __ATOMIC_RELAXED, __HIP_MEMORY_SCOPE_AGENT);
        tv = __hip_atomic_load(&ws[T_OFF + idx], __ATOMIC_RELAXED, __HIP_MEMORY_SCOPE_AGENT);
        iv = __hip_atomic_load(&ws[I_OFF + idx], __ATOMIC_RELAXED, __HIP_MEMORY_SCOPE_AGENT);
    }
#pragma unroll
    for (int off = 16; off > 0; off >>= 1) {  // lanes 32..63 hold zeros
        pv += __shfl_down(pv, off, 64);
        tv += __shfl_down(tv, off, 64);
        iv += __shfl_down(iv, off, 64);
    }

    int last2flag = 0;
    if (lane == 0) {
        const float dice_loss = 1.0f - (2.0f * iv + 1.0f) / (pv + tv + 1.0f);
        const float zero_loss = pv / (float)N_PER_BATCH;
        // target is 0/1 -> tv is an exact integer in fp32, ==0 test is exact
        const float loss_b = (tv == 0.0f) ? zero_loss : dice_loss;
        __hip_atomic_store(&ws[LOSS_OFF + b], loss_b, __ATOMIC_RELAXED, __HIP_MEMORY_SCOPE_AGENT);
        asm volatile("s_waitcnt vmcnt(0)" ::: "memory");
        const unsigned old2 = __hip_atomic_fetch_add(&u[L2_OFF_U32], 1u,
                                                     __ATOMIC_RELAXED, __HIP_MEMORY_SCOPE_AGENT);
        last2flag = (old2 == NBATCH - 1) ? 1 : 0;
    }
    const int last2 = __shfl(last2flag, 0, 64);
    if (!last2) return;          // 63 of 64 batch finishers exit here

    // ---- global finisher: mean over 64 batch losses ----
    float l = __hip_atomic_load(&ws[LOSS_OFF + lane], __ATOMIC_RELAXED, __HIP_MEMORY_SCOPE_AGENT);
#pragma unroll
    for (int off = 32; off > 0; off >>= 1) l += __shfl_down(l, off, 64);
    if (lane == 0) out[0] = l * (1.0f / (float)NBATCH);
}

extern "C" void kernel_launch(void* const* d_in, const int* in_sizes, int n_in,
                              void* d_out, int out_size, void* d_ws, size_t ws_size,
                              hipStream_t stream) {
    const float* pred = (const float*)d_in[0];
    const float* tgt  = (const float*)d_in[1];
    float* out = (float*)d_out;
    float* ws  = (float*)d_ws;

    // zero only the ticket-counter region (graph-capturable async memset)
    hipMemsetAsync(d_ws, 0, CLEAR_BYTES, stream);
    dice_fused<<<GRID, THREADS, 0, stream>>>(pred, tgt, ws, out);
}

// Round 7
// 26.397 us; speedup vs baseline: 3.5853x; 1.2184x over previous
//
#include <hip/hip_runtime.h>

#define N_PER_BATCH (512 * 512)        // 262144
#define BLOCKS_PER_BATCH 32
#define NBATCH 64
#define THREADS 256
// per block: 262144/32 = 8192 elems = 2048 float4; per thread: 8 float4 per array

__global__ __launch_bounds__(THREADS) void dice_stage1(
    const float* __restrict__ pred, const float* __restrict__ tgt,
    float* __restrict__ partial) {
    const int b  = blockIdx.x >> 5;          // / BLOCKS_PER_BATCH
    const int cb = blockIdx.x & 31;          // % BLOCKS_PER_BATCH

    const float4* p4 = reinterpret_cast<const float4*>(pred + (size_t)b * N_PER_BATCH);
    const float4* t4 = reinterpret_cast<const float4*>(tgt  + (size_t)b * N_PER_BATCH);

    const int base = cb * (N_PER_BATCH / BLOCKS_PER_BATCH / 4);  // 2048 float4 per block

    // Issue all 16 loads before any use: deep memory-level parallelism.
    float4 p[8], t[8];
#pragma unroll
    for (int i = 0; i < 8; ++i) p[i] = p4[base + i * THREADS + threadIdx.x];
#pragma unroll
    for (int i = 0; i < 8; ++i) t[i] = t4[base + i * THREADS + threadIdx.x];

    float ps = 0.f, ts = 0.f, is = 0.f;
#pragma unroll
    for (int i = 0; i < 8; ++i) {
        ps += (p[i].x + p[i].y) + (p[i].z + p[i].w);
        ts += (t[i].x + t[i].y) + (t[i].z + t[i].w);
        is += (p[i].x * t[i].x + p[i].y * t[i].y) + (p[i].z * t[i].z + p[i].w * t[i].w);
    }

    // wave64 butterfly reduce
#pragma unroll
    for (int off = 32; off > 0; off >>= 1) {
        ps += __shfl_down(ps, off, 64);
        ts += __shfl_down(ts, off, 64);
        is += __shfl_down(is, off, 64);
    }

    __shared__ float s[3][4];
    const int wid  = threadIdx.x >> 6;
    const int lane = threadIdx.x & 63;
    if (lane == 0) { s[0][wid] = ps; s[1][wid] = ts; s[2][wid] = is; }
    __syncthreads();
    if (threadIdx.x == 0) {
        const float P = (s[0][0] + s[0][1]) + (s[0][2] + s[0][3]);
        const float T = (s[1][0] + s[1][1]) + (s[1][2] + s[1][3]);
        const float I = (s[2][0] + s[2][1]) + (s[2][2] + s[2][3]);
        float* o = partial + ((size_t)b * BLOCKS_PER_BATCH + cb) * 3;
        o[0] = P; o[1] = T; o[2] = I;
    }
}

__global__ __launch_bounds__(64) void dice_stage2(
    const float* __restrict__ partial, float* __restrict__ out) {
    const int b = threadIdx.x;  // 0..63 — one lane per batch
    float P = 0.f, T = 0.f, I = 0.f;
#pragma unroll
    for (int i = 0; i < BLOCKS_PER_BATCH; ++i) {
        const float* p = partial + ((size_t)b * BLOCKS_PER_BATCH + i) * 3;
        P += p[0]; T += p[1]; I += p[2];
    }
    const float dice_loss = 1.0f - (2.0f * I + 1.0f) / (P + T + 1.0f);
    const float zero_loss = P / (float)N_PER_BATCH;
    // target entries are 0/1 -> T is an exact small integer in fp32, so ==0 is exact
    float loss = (T == 0.0f) ? zero_loss : dice_loss;
#pragma unroll
    for (int off = 32; off > 0; off >>= 1) loss += __shfl_down(loss, off, 64);
    if (b == 0) out[0] = loss * (1.0f / (float)NBATCH);
}

extern "C" void kernel_launch(void* const* d_in, const int* in_sizes, int n_in,
                              void* d_out, int out_size, void* d_ws, size_t ws_size,
                              hipStream_t stream) {
    const float* pred = (const float*)d_in[0];
    const float* tgt  = (const float*)d_in[1];
    float* out = (float*)d_out;
    float* partial = (float*)d_ws;  // 64 * 32 * 3 floats = 24 KiB

    dice_stage1<<<NBATCH * BLOCKS_PER_BATCH, THREADS, 0, stream>>>(pred, tgt, partial);
    dice_stage2<<<1, 64, 0, stream>>>(partial, out);
}

// Round 8
// 26.238 us; speedup vs baseline: 3.6071x; 1.0061x over previous
//
#include <hip/hip_runtime.h>

#define N_PER_BATCH (512 * 512)        // 262144
#define BPB 32                          // blocks (chunks) per batch
#define NBATCH 64
#define THREADS 256
#define GRID (NBATCH * BPB)             // 2048

// d_ws: three SoA planes of GRID floats, indexed [chunk*NBATCH + batch] so
// stage2's lanes (one per batch) read fully coalesced:
//   P at [0, 2048), T at [2048, 4096), I at [4096, 6144)   -- 24 KiB
#define P_OFF 0
#define T_OFF GRID
#define I_OFF (2 * GRID)

__global__ __launch_bounds__(THREADS) void dice_stage1(
    const float* __restrict__ pred, const float* __restrict__ tgt,
    float* __restrict__ partial) {
    const int b  = blockIdx.x >> 5;          // / BPB
    const int cb = blockIdx.x & 31;          // % BPB

    const float4* p4 = reinterpret_cast<const float4*>(pred + (size_t)b * N_PER_BATCH);
    const float4* t4 = reinterpret_cast<const float4*>(tgt  + (size_t)b * N_PER_BATCH);
    const int base = cb * (N_PER_BATCH / BPB / 4);   // 2048 float4 per block

    // all 16 loads issued before use: deep MLP
    float4 p[8], t[8];
#pragma unroll
    for (int i = 0; i < 8; ++i) p[i] = p4[base + i * THREADS + threadIdx.x];
#pragma unroll
    for (int i = 0; i < 8; ++i) t[i] = t4[base + i * THREADS + threadIdx.x];

    float ps = 0.f, ts = 0.f, is = 0.f;
#pragma unroll
    for (int i = 0; i < 8; ++i) {
        ps += (p[i].x + p[i].y) + (p[i].z + p[i].w);
        ts += (t[i].x + t[i].y) + (t[i].z + t[i].w);
        is += (p[i].x * t[i].x + p[i].y * t[i].y) + (p[i].z * t[i].z + p[i].w * t[i].w);
    }

#pragma unroll
    for (int off = 32; off > 0; off >>= 1) {
        ps += __shfl_down(ps, off, 64);
        ts += __shfl_down(ts, off, 64);
        is += __shfl_down(is, off, 64);
    }

    __shared__ float s[3][4];
    const int wid  = threadIdx.x >> 6;
    const int lane = threadIdx.x & 63;
    if (lane == 0) { s[0][wid] = ps; s[1][wid] = ts; s[2][wid] = is; }
    __syncthreads();
    if (threadIdx.x == 0) {
        const float P = (s[0][0] + s[0][1]) + (s[0][2] + s[0][3]);
        const float T = (s[1][0] + s[1][1]) + (s[1][2] + s[1][3]);
        const float I = (s[2][0] + s[2][1]) + (s[2][2] + s[2][3]);
        const int idx = cb * NBATCH + b;   // SoA, lane-contiguous in b
        partial[P_OFF + idx] = P;
        partial[T_OFF + idx] = T;
        partial[I_OFF + idx] = I;
    }
}

__global__ __launch_bounds__(THREADS) void dice_stage2(
    const float* __restrict__ partial, float* __restrict__ out) {
    const int g    = threadIdx.x >> 6;   // 4 groups; group g sums chunks g*8..g*8+7
    const int lane = threadIdx.x & 63;   // lane owns batch `lane`

    float P = 0.f, T = 0.f, I = 0.f;
#pragma unroll
    for (int i = 0; i < 8; ++i) {
        const int idx = (g * 8 + i) * NBATCH + lane;   // coalesced across lanes
        P += partial[P_OFF + idx];
        T += partial[T_OFF + idx];
        I += partial[I_OFF + idx];
    }

    __shared__ float r[3][4][64];
    r[0][g][lane] = P; r[1][g][lane] = T; r[2][g][lane] = I;
    __syncthreads();
    if (threadIdx.x < 64) {
        const float Ps = (r[0][0][lane] + r[0][1][lane]) + (r[0][2][lane] + r[0][3][lane]);
        const float Ts = (r[1][0][lane] + r[1][1][lane]) + (r[1][2][lane] + r[1][3][lane]);
        const float Is = (r[2][0][lane] + r[2][1][lane]) + (r[2][2][lane] + r[2][3][lane]);
        const float dice_loss = 1.0f - (2.0f * Is + 1.0f) / (Ps + Ts + 1.0f);
        const float zero_loss = Ps / (float)N_PER_BATCH;
        // target is 0/1 -> Ts is an exact integer in fp32, ==0 test is exact
        float loss = (Ts == 0.0f) ? zero_loss : dice_loss;
#pragma unroll
        for (int off = 32; off > 0; off >>= 1) loss += __shfl_down(loss, off, 64);
        if (lane == 0) out[0] = loss * (1.0f / (float)NBATCH);
    }
}

extern "C" void kernel_launch(void* const* d_in, const int* in_sizes, int n_in,
                              void* d_out, int out_size, void* d_ws, size_t ws_size,
                              hipStream_t stream) {
    const float* pred = (const float*)d_in[0];
    const float* tgt  = (const float*)d_in[1];
    float* out = (float*)d_out;
    float* partial = (float*)d_ws;  // 3 * 2048 * 4 B = 24 KiB

    dice_stage1<<<GRID, THREADS, 0, stream>>>(pred, tgt, partial);
    dice_stage2<<<1, THREADS, 0, stream>>>(partial, out);
}